// Round 11
// baseline (28.005 us; speedup 1.0000x reference)
//
#include <hip/hip_runtime.h>

typedef __attribute__((ext_vector_type(4))) float f32x4;

constexpr int Bdim = 8192;   // rows of x
constexpr int Cdim = 4096;   // rows of W (= output cols)
constexpr int Ddim = 256;    // K

// 15*exp(-t) == +0.0f in f32 (incl. denormal range) for t >= ~106.7; margin -> 112.
constexpr float ZERO_THRESH = 112.0f;

// ---------------------------------------------------------------------------
// Kernel 1: per-block partial max of ||W_c||^2 — the ONLY global dependency.
// 1024 blocks x 4 W rows (one wave/row). Reads 4 MB, writes 4 KB.
// ---------------------------------------------------------------------------
__global__ __launch_bounds__(256) void wmax_kernel(const float* __restrict__ W,
                                                   float* __restrict__ pmax) {
  __shared__ float sm[4];
  int tid  = threadIdx.x;
  int lane = tid & 63;
  int wid  = tid >> 6;
  int row  = blockIdx.x * 4 + wid;
  f32x4 v = *(const f32x4*)(W + (size_t)row * Ddim + lane * 4);
  float s = v[0]*v[0] + v[1]*v[1] + v[2]*v[2] + v[3]*v[3];
  #pragma unroll
  for (int off = 32; off > 0; off >>= 1) s += __shfl_xor(s, off, 64);
  if (lane == 0) sm[wid] = s;
  __syncthreads();
  if (tid == 0) pmax[blockIdx.x] = fmaxf(fmaxf(sm[0], sm[1]), fmaxf(sm[2], sm[3]));
}

// ---------------------------------------------------------------------------
// Kernel 2: 2048 blocks x 4 output rows; each WAVE exclusively owns one row
// (16 KB contiguous). No LDS, no block barrier (a barrier would force a
// vmcnt(0) drain into the store stream).
// Order per wave:
//   1. issue independent loads (own x row 1 KB; pmax[1024] 4x16B)
//   2. UNCONDITIONAL zero fill of the row — stores have no input deps, so
//      the store stream starts immediately (fill-kernel profile; regular
//      stores — NT stores measured -25% in R5)
//   3. in-wave reduces: row norm (sum) and global max||W||^2 (max)
//   4. per-row Cauchy-Schwarz screen: ||x_b - w_c||^2 >= (||x_b||-max||W||)^2
//      > 112  =>  every output of the row is exactly 15*exp(-metric) == +0.0f
//      in f32  =>  the zeros already written are the exact output -> return.
//   5. slow path (wave-uniform; never taken for the bench input): wait
//      vmcnt(0) so the zeros are committed, then overwrite the row with the
//      exact f32 metric (x broadcast from registers via shuffles).
// ---------------------------------------------------------------------------
__global__ __launch_bounds__(256) void rbf_fill(const float* __restrict__ x,
                                                const float* __restrict__ W,
                                                const float* __restrict__ pmax,
                                                float* __restrict__ out) {
  int tid  = threadIdx.x;
  int lane = tid & 63;
  int wid  = tid >> 6;
  int row  = blockIdx.x * 4 + wid;          // wave-exclusive output row

  // 1) independent loads issued up front
  f32x4 v = *(const f32x4*)(x + (size_t)row * Ddim + lane * 4);
  const f32x4* pm4 = (const f32x4*)pmax;    // 256 f32x4 = 1024 f32
  f32x4 q0 = pm4[lane];
  f32x4 q1 = pm4[lane + 64];
  f32x4 q2 = pm4[lane + 128];
  f32x4 q3 = pm4[lane + 192];

  // 2) unconditional zero fill of this wave's row (4096 f32 = 16 KB)
  f32x4 z = {0.0f, 0.0f, 0.0f, 0.0f};
  float* base = out + (size_t)row * Cdim + lane * 4;
  #pragma unroll
  for (int p = 0; p < 16; ++p)
    *(f32x4*)(base + (size_t)p * 256) = z;

  // 3) in-wave reduces
  float s = v[0]*v[0] + v[1]*v[1] + v[2]*v[2] + v[3]*v[3];
  #pragma unroll
  for (int off = 32; off > 0; off >>= 1) s += __shfl_xor(s, off, 64);

  float wmx = fmaxf(fmaxf(fmaxf(q0[0], q0[1]), fmaxf(q0[2], q0[3])),
                    fmaxf(fmaxf(q1[0], q1[1]), fmaxf(q1[2], q1[3])));
  wmx = fmaxf(wmx, fmaxf(fmaxf(fmaxf(q2[0], q2[1]), fmaxf(q2[2], q2[3])),
                         fmaxf(fmaxf(q3[0], q3[1]), fmaxf(q3[2], q3[3]))));
  #pragma unroll
  for (int off = 32; off > 0; off >>= 1) wmx = fmaxf(wmx, __shfl_xor(wmx, off, 64));

  // 4) per-row screen (s, wmx wave-uniform after full butterfly)
  float gap = sqrtf(s) - sqrtf(wmx);
  if (gap > 0.0f && gap * gap > ZERO_THRESH) return;   // zeros are exact

  // 5) slow path (wave-uniform branch; not taken for the bench input)
  asm volatile("s_waitcnt vmcnt(0)" ::: "memory");     // zeros committed first
  for (int c0 = 0; c0 < Cdim; c0 += 64) {
    int col = c0 + lane;
    const float* wrow = W + (size_t)col * Ddim;
    float m = 0.0f;
    for (int d = 0; d < Ddim; d += 4) {
      f32x4 wv = *(const f32x4*)(wrow + d);
      int src = d >> 2;                                // lane holding x[row][d..d+3]
      #pragma unroll
      for (int e = 0; e < 4; ++e) {
        float xd = __shfl(v[e], src, 64);
        float df = wv[e] - xd;
        m += df * df;
      }
    }
    out[(size_t)row * Cdim + col] = 15.0f * expf(-m);
  }
}

extern "C" void kernel_launch(void* const* d_in, const int* in_sizes, int n_in,
                              void* d_out, int out_size, void* d_ws, size_t ws_size,
                              hipStream_t stream) {
  const float* x = (const float*)d_in[0];   // [8192, 256] f32
  const float* W = (const float*)d_in[1];   // [4096, 256] f32
  float* out     = (float*)d_out;           // [8192, 4096] f32
  float* pmax    = (float*)d_ws;            // 1024 f32 = 4 KB scratch

  // 1) W-norm partial maxes only (4 MB read — the single global dependency)
  wmax_kernel<<<Cdim / 4, 256, 0, stream>>>(W, pmax);

  // 2) unconditional-fill + in-wave screen: 2048 blocks x 4 wave-owned rows
  rbf_fill<<<Bdim / 4, 256, 0, stream>>>(x, W, pmax, out);
}